// Round 1
// baseline (161.554 us; speedup 1.0000x reference)
//
#include <hip/hip_runtime.h>
#include <hip/hip_bf16.h>
#include <math.h>

#define DIM  64
#define KN   16
#define NREL 32

__device__ __forceinline__ float frcp(float x) { return __builtin_amdgcn_rcpf(x); }

__device__ __forceinline__ unsigned short f2bf(float f) {
    unsigned u = __float_as_uint(f);
    u = (u + 0x7fffu + ((u >> 16) & 1u)) >> 16;   // RNE
    return (unsigned short)u;
}
// bf16 pair packed in a dword: low ushort = even dim, high ushort = odd dim
__device__ __forceinline__ float bflo(unsigned v) { return __uint_as_float(v << 16); }
__device__ __forceinline__ float bfhi(unsigned v) { return __uint_as_float(v & 0xffff0000u); }

// ============================================================================
// Kernel 1: WEb[e][d] = bf16( sum_j W[d][j] * entity_emb[e][j] )  (unchanged)
// ============================================================================
__global__ __launch_bounds__(256, 4) void we_kernel(
    const float* __restrict__ entity_emb,
    const float* __restrict__ W,
    unsigned short* __restrict__ WEb,
    int nRows)
{
    __shared__ float4 xs_s[4][8 * 16];
    const int tid  = threadIdx.x;
    const int wave = tid >> 6;
    const int lane = tid & 63;
    float4* xs = xs_s[wave];

    const int base = (blockIdx.x * 4 + wave) * 8;
    if (base >= nRows) return;

    float4 Wr[16];
    const float4* W4 = (const float4*)(W + lane * DIM);
    #pragma unroll
    for (int j = 0; j < 16; ++j) Wr[j] = W4[j];

    const float4* src = (const float4*)entity_emb;
    #pragma unroll
    for (int i = 0; i < 2; ++i) {
        const int idx = i * 64 + lane;
        const int row = base + (idx >> 4);
        const size_t g = (row < nRows) ? ((size_t)base * 16 + idx) : 0;
        xs[idx] = src[g];
    }
    asm volatile("s_waitcnt lgkmcnt(0)" ::: "memory");

    #pragma unroll
    for (int r = 0; r < 8; ++r) {
        const int row = base + r;
        if (row >= nRows) break;
        float h0 = 0.f, h1 = 0.f, h2 = 0.f, h3 = 0.f;
        #pragma unroll
        for (int jc = 0; jc < 16; jc += 4) {
            float4 a = xs[r * 16 + jc + 0];
            float4 b = xs[r * 16 + jc + 1];
            float4 c = xs[r * 16 + jc + 2];
            float4 d = xs[r * 16 + jc + 3];
            h0 += a.x*Wr[jc+0].x + a.y*Wr[jc+0].y + a.z*Wr[jc+0].z + a.w*Wr[jc+0].w;
            h1 += b.x*Wr[jc+1].x + b.y*Wr[jc+1].y + b.z*Wr[jc+1].z + b.w*Wr[jc+1].w;
            h2 += c.x*Wr[jc+2].x + c.y*Wr[jc+2].y + c.z*Wr[jc+2].z + c.w*Wr[jc+2].w;
            h3 += d.x*Wr[jc+3].x + d.y*Wr[jc+3].y + d.z*Wr[jc+3].z + d.w*Wr[jc+3].w;
        }
        WEb[(size_t)row * DIM + lane] = f2bf((h0 + h1) + (h2 + h3));
    }
}

// ============================================================================
// Kernel 2 (R12): 1 BLOCK per pair, 4 waves. Wave w owns hop-1 groups
// gm = 4*w + qq (one per 16-lane quarter), so the per-wave gather critical
// path is 4x shorter than R11 and the grid is 4x larger (4096 blocks).
// Target 32 waves/CU via __launch_bounds__(256, 8) — latency hiding was the
// bottleneck theory. Wave 3 also does hop-0 (pre-barrier) and the tail.
// ============================================================================
__global__ __launch_bounds__(256, 8) void kgcn_main(
    const int* __restrict__ pairs,
    const int* __restrict__ adjE,
    const int* __restrict__ adjR,
    const unsigned short* __restrict__ WEb,
    const float* __restrict__ relation_emb,
    const float* __restrict__ user_emb,
    const float* __restrict__ W,
    const float* __restrict__ bias,
    float* __restrict__ out,
    int nPairs)
{
    // ev1 padded to 68 floats/row: row stride 272 B breaks the 4-way bank
    // conflict of quarter-strided float4 writes (row stride 256 B -> bank 0).
    __shared__ float ev1_s[KN * 68];
    __shared__ float xb_s[DIM];

    const int tid  = threadIdx.x;
    const int wave = tid >> 6;
    const int lane = tid & 63;
    const int p    = blockIdx.x;
    if (p >= nPairs) return;              // uniform across block (pre-barrier)

    const int qq = lane >> 4;             // quarter-wave id (0..3)
    const int c  = lane & 15;             // uint2 column within a WE row
    const int c4 = c * 4;                 // first owned dim

    const int user = pairs[2 * p + 0];
    const int item = pairs[2 * p + 1];

    const float4 b4 = *(const float4*)(bias + c4);
    const uint2* WEq = (const uint2*)WEb;   // row e starts at e*16 uint2

    // item adjacency row (replicated per wave; lanes 0..15 hold it)
    int rk0 = 0, e1 = 0;
    if (lane < KN) {
        rk0 = adjR[(size_t)item * KN + lane];
        e1  = adjE[(size_t)item * KN + lane];
    }

    // dot(u, rel_r) for all 32 relations: 2 lanes per relation (replicated/wave)
    float acc;
    {
        const int r = lane >> 1, hlf = lane & 1;
        const float4* rel4 = (const float4*)(relation_emb + r * DIM + hlf * 32);
        const float4* u4   = (const float4*)(user_emb + (size_t)user * DIM + hlf * 32);
        float a0 = 0.f, a1 = 0.f;
        #pragma unroll
        for (int j = 0; j < 8; j += 2) {
            float4 a = rel4[j],      b = u4[j];
            float4 cc = rel4[j + 1], d = u4[j + 1];
            a0 += a.x*b.x + a.y*b.y + a.z*b.z + a.w*b.w;
            a1 += cc.x*d.x + cc.y*d.y + cc.z*d.z + cc.w*d.w;
        }
        acc = a0 + a1;
        acc += __shfl_xor(acc, 1);
    }

    // softmax within 16-lane subgroups (4 independent groups per call)
    auto softmax16 = [&](float s) -> float {
        float mx = s;
        mx = fmaxf(mx, __shfl_xor(mx, 1));
        mx = fmaxf(mx, __shfl_xor(mx, 2));
        mx = fmaxf(mx, __shfl_xor(mx, 4));
        mx = fmaxf(mx, __shfl_xor(mx, 8));
        float e = __expf(s - mx);
        float ss = e;
        ss += __shfl_xor(ss, 1);
        ss += __shfl_xor(ss, 2);
        ss += __shfl_xor(ss, 4);
        ss += __shfl_xor(ss, 8);
        return e * frcp(ss);
    };

    // ---- wave 3 issues hop-0 gather loads EARLY so they fly with the
    // hop-1 gathers below.
    uint2 itemv = make_uint2(0u, 0u);
    uint2 h0v[4];
    if (wave == 3) {
        itemv = WEq[(size_t)item * 16 + c];
        #pragma unroll
        for (int k = 0; k < 4; ++k) {
            const int e = __shfl(e1, qq * 4 + k);
            h0v[k] = WEq[(size_t)(unsigned)e * 16 + c];
        }
    }

    // ---- this wave's hop-1 group (one per quarter): gm = 4*wave + qq ----
    const int gm = wave * 4 + qq;
    const int gs = __shfl(e1, gm);        // group's self entity
    const int rkA = adjR[(size_t)(unsigned)gs * KN + c];
    const int ekA = adjE[(size_t)(unsigned)gs * KN + c];

    const float wA = softmax16(__shfl(acc, rkA << 1));

    // self row + 16 weighted neighbor rows (each load: 4 rows/wave, 512 B)
    uint2 sv = WEq[(size_t)(unsigned)gs * 16 + c];
    float ax = b4.x + bflo(sv.x);
    float ay = b4.y + bfhi(sv.x);
    float az = b4.z + bflo(sv.y);
    float aw = b4.w + bfhi(sv.y);
    #pragma unroll
    for (int k = 0; k < KN; ++k) {
        const int   e = __shfl(ekA, qq * 16 + k);
        const float w = __shfl(wA,  qq * 16 + k);
        uint2 v = WEq[(size_t)(unsigned)e * 16 + c];
        ax += w * bflo(v.x);
        ay += w * bfhi(v.x);
        az += w * bflo(v.y);
        aw += w * bfhi(v.y);
    }
    *(float4*)&ev1_s[gm * 68 + c4] =
        make_float4(fmaxf(ax, 0.f), fmaxf(ay, 0.f), fmaxf(az, 0.f), fmaxf(aw, 0.f));

    // ---- wave 3: finish hop-0 BEFORE the barrier (independent of ev1) ----
    float w0 = 0.f, e0x = 0.f, e0y = 0.f, e0z = 0.f, e0w = 0.f;
    if (wave == 3) {
        w0 = softmax16(__shfl(acc, rk0 << 1));
        float bx = 0.f, by = 0.f, bz = 0.f, bw = 0.f;
        #pragma unroll
        for (int k = 0; k < 4; ++k) {
            const float w = __shfl(w0, qq * 4 + k);
            bx += w * bflo(h0v[k].x);
            by += w * bfhi(h0v[k].x);
            bz += w * bflo(h0v[k].y);
            bw += w * bfhi(h0v[k].y);
        }
        bx += __shfl_xor(bx, 16); by += __shfl_xor(by, 16);
        bz += __shfl_xor(bz, 16); bw += __shfl_xor(bw, 16);
        bx += __shfl_xor(bx, 32); by += __shfl_xor(by, 32);
        bz += __shfl_xor(bz, 32); bw += __shfl_xor(bw, 32);
        bx += bflo(itemv.x) + b4.x;
        by += bfhi(itemv.x) + b4.y;
        bz += bflo(itemv.y) + b4.z;
        bw += bfhi(itemv.y) + b4.w;
        e0x = fmaxf(bx, 0.f); e0y = fmaxf(by, 0.f);
        e0z = fmaxf(bz, 0.f); e0w = fmaxf(bw, 0.f);
    }

    __syncthreads();                      // ev1 complete, visible block-wide
    if (wave != 3) return;                // tail is one wave

    // ---- layer 1 aggregate: x1 = e0 + sum_k w0_k * ev1_k (quarter-split)
    float sx = 0.f, sy = 0.f, sz = 0.f, sw = 0.f;
    #pragma unroll
    for (int k = 0; k < 4; ++k) {
        const int   kg = qq * 4 + k;
        const float w  = __shfl(w0, kg);
        float4 ev = *(const float4*)&ev1_s[kg * 68 + c4];
        sx += w * ev.x;
        sy += w * ev.y;
        sz += w * ev.z;
        sw += w * ev.w;
    }
    sx += __shfl_xor(sx, 16); sy += __shfl_xor(sy, 16);
    sz += __shfl_xor(sz, 16); sw += __shfl_xor(sw, 16);
    sx += __shfl_xor(sx, 32); sy += __shfl_xor(sy, 32);
    sz += __shfl_xor(sz, 32); sw += __shfl_xor(sw, 32);

    // ---- the ONE real matvec: h1 = W x1 + b, via LDS broadcast ----
    asm volatile("s_waitcnt lgkmcnt(0)" ::: "memory");
    if (qq == 0)
        *(float4*)&xb_s[c4] = make_float4(e0x + sx, e0y + sy, e0z + sz, e0w + sw);
    asm volatile("s_waitcnt lgkmcnt(0)" ::: "memory");
    float h0 = bias[lane], h1 = 0.f, h2 = 0.f, h3 = 0.f;
    {
        const float4* Wl  = (const float4*)(W + lane * DIM);
        const float4* xv4 = (const float4*)xb_s;
        #pragma unroll
        for (int j = 0; j < 16; j += 4) {
            float4 w0v = Wl[j],   x0v = xv4[j];
            float4 w1v = Wl[j+1], x1v = xv4[j+1];
            float4 w2v = Wl[j+2], x2v = xv4[j+2];
            float4 w3v = Wl[j+3], x3v = xv4[j+3];
            h0 += w0v.x*x0v.x + w0v.y*x0v.y + w0v.z*x0v.z + w0v.w*x0v.w;
            h1 += w1v.x*x1v.x + w1v.y*x1v.y + w1v.z*x1v.z + w1v.w*x1v.w;
            h2 += w2v.x*x2v.x + w2v.y*x2v.y + w2v.z*x2v.z + w2v.w*x2v.w;
            h3 += w3v.x*x3v.x + w3v.y*x3v.y + w3v.z*x3v.z + w3v.w*x3v.w;
        }
    }
    const float itemf = tanhf((h0 + h1) + (h2 + h3));

    float d = user_emb[(size_t)user * DIM + lane] * itemf;
    d += __shfl_xor(d, 1);
    d += __shfl_xor(d, 2);
    d += __shfl_xor(d, 4);
    d += __shfl_xor(d, 8);
    d += __shfl_xor(d, 16);
    d += __shfl_xor(d, 32);
    if (lane == 0) out[p] = 1.f / (1.f + expf(-d));
}

// ============================================================================
// Fallback (verified R5 kernel) in case ws_size < WE table size.
// ============================================================================
__global__ __launch_bounds__(256, 4) void kgcn_fallback(
    const int* __restrict__ pairs, const int* __restrict__ adj_entity,
    const int* __restrict__ adj_relation, const float* __restrict__ entity_emb,
    const float* __restrict__ relation_emb, const float* __restrict__ user_emb,
    const float* __restrict__ W, const float* __restrict__ bias,
    float* __restrict__ out, int nPairs)
{
    __shared__ float ev1_s[2][KN * DIM];
    __shared__ float xb_s[4][DIM];
    const int tid = threadIdx.x, wave = tid >> 6, lane = tid & 63;
    const int q = wave >> 1, half = wave & 1;
    int p = blockIdx.x * 2 + q;
    if (p >= nPairs) p = nPairs - 1;
    float* ev1 = ev1_s[q]; float* xb = xb_s[wave];
    const int user = pairs[2 * p + 0], item = pairs[2 * p + 1];
    const float bval = bias[lane];
    const float* emb_l = entity_emb + lane;
    const float4* W4 = (const float4*)(W + lane * DIM);
    int rk0 = 0, e1 = 0;
    if (lane < KN) {
        rk0 = adj_relation[(size_t)item * KN + lane];
        e1  = adj_entity[(size_t)item * KN + lane];
    }
    float acc;
    {
        const int r = lane >> 1, hlf = lane & 1;
        const float4* rel4 = (const float4*)(relation_emb + r * DIM + hlf * 32);
        const float4* u4 = (const float4*)(user_emb + (size_t)user * DIM + hlf * 32);
        float a0 = 0.f, a1 = 0.f;
        #pragma unroll
        for (int j = 0; j < 8; j += 2) {
            float4 a = rel4[j], b = u4[j], c = rel4[j+1], d = u4[j+1];
            a0 += a.x*b.x + a.y*b.y + a.z*b.z + a.w*b.w;
            a1 += c.x*d.x + c.y*d.y + c.z*d.z + c.w*d.w;
        }
        acc = a0 + a1; acc += __shfl_xor(acc, 1);
    }
    auto softmax16 = [&](float s) -> float {
        float mx = s;
        mx = fmaxf(mx, __shfl_xor(mx, 1)); mx = fmaxf(mx, __shfl_xor(mx, 2));
        mx = fmaxf(mx, __shfl_xor(mx, 4)); mx = fmaxf(mx, __shfl_xor(mx, 8));
        float e = __expf(s - mx);
        float ss = e;
        ss += __shfl_xor(ss, 1); ss += __shfl_xor(ss, 2);
        ss += __shfl_xor(ss, 4); ss += __shfl_xor(ss, 8);
        return e * frcp(ss);
    };
    auto matvec = [&](float xv) -> float {
        asm volatile("s_waitcnt lgkmcnt(0)" ::: "memory");
        xb[lane] = xv;
        asm volatile("s_waitcnt lgkmcnt(0)" ::: "memory");
        float h0 = bval, h1 = 0.f, h2 = 0.f, h3 = 0.f;
        const float4* xv4 = (const float4*)xb;
        #pragma unroll
        for (int j = 0; j < 16; j += 4) {
            float4 w0 = W4[j], x0 = xv4[j], w1 = W4[j+1], x1 = xv4[j+1];
            float4 w2 = W4[j+2], x2 = xv4[j+2], w3 = W4[j+3], x3 = xv4[j+3];
            h0 += w0.x*x0.x + w0.y*x0.y + w0.z*x0.z + w0.w*x0.w;
            h1 += w1.x*x1.x + w1.y*x1.y + w1.z*x1.z + w1.w*x1.w;
            h2 += w2.x*x2.x + w2.y*x2.y + w2.z*x2.z + w2.w*x2.w;
            h3 += w3.x*x3.x + w3.y*x3.y + w3.z*x3.z + w3.w*x3.w;
        }
        return (h0 + h1) + (h2 + h3);
    };
    auto gather = [&](int self, int ek, float w) -> float {
        float xa = emb_l[(size_t)(unsigned)self * DIM], xc = 0.f;
        #pragma unroll
        for (int k = 0; k < KN; k += 2) {
            const int e0i = __shfl(ek, k); const float f0 = __shfl(w, k);
            const int e1i = __shfl(ek, k + 1); const float f1 = __shfl(w, k + 1);
            xa += f0 * emb_l[(size_t)(unsigned)e0i * DIM];
            xc += f1 * emb_l[(size_t)(unsigned)e1i * DIM];
        }
        return xa + xc;
    };
    int rk_n = 0, ek_n = 0;
    {
        const int g0 = __shfl(e1, half * 8);
        if (lane < KN) {
            rk_n = adj_relation[(size_t)(unsigned)g0 * KN + lane];
            ek_n = adj_entity[(size_t)(unsigned)g0 * KN + lane];
        }
    }
    #pragma unroll 1
    for (int mi = 0; mi < 8; ++mi) {
        const int m = half * 8 + mi;
        const int g = __shfl(e1, m);
        const int rk = rk_n, ek = ek_n;
        if (mi + 1 < 8) {
            const int gn = __shfl(e1, m + 1);
            if (lane < KN) {
                rk_n = adj_relation[(size_t)(unsigned)gn * KN + lane];
                ek_n = adj_entity[(size_t)(unsigned)gn * KN + lane];
            }
        }
        const float w = softmax16(__shfl(acc, rk << 1));
        const float x = gather(g, ek, w);
        ev1[m * DIM + lane] = fmaxf(matvec(x), 0.f);
    }
    __syncthreads();
    if (half != 0) return;
    const float w0 = softmax16(__shfl(acc, rk0 << 1));
    const float x0 = gather(item, e1, w0);
    const float e0 = fmaxf(matvec(x0), 0.f);
    float xa = e0, xc = 0.f;
    #pragma unroll
    for (int k = 0; k < KN; k += 2) {
        xa += __shfl(w0, k) * ev1[k * DIM + lane];
        xc += __shfl(w0, k + 1) * ev1[(k + 1) * DIM + lane];
    }
    const float itemf = tanhf(matvec(xa + xc));
    float d = user_emb[(size_t)user * DIM + lane] * itemf;
    d += __shfl_xor(d, 1); d += __shfl_xor(d, 2); d += __shfl_xor(d, 4);
    d += __shfl_xor(d, 8); d += __shfl_xor(d, 16); d += __shfl_xor(d, 32);
    if (lane == 0) out[p] = 1.f / (1.f + expf(-d));
}

extern "C" void kernel_launch(void* const* d_in, const int* in_sizes, int n_in,
                              void* d_out, int out_size, void* d_ws, size_t ws_size,
                              hipStream_t stream) {
    const int*   pairs        = (const int*)d_in[0];
    const int*   adj_entity   = (const int*)d_in[1];
    const int*   adj_relation = (const int*)d_in[2];
    const float* entity_emb   = (const float*)d_in[3];
    const float* relation_emb = (const float*)d_in[4];
    const float* user_emb     = (const float*)d_in[5];
    const float* W            = (const float*)d_in[6];
    const float* b            = (const float*)d_in[7];
    float* out = (float*)d_out;

    const int nPairs = in_sizes[0] / 2;          // pairs is (B, 2)
    const int nEnt   = in_sizes[3] / DIM;        // entity count
    const size_t weBytes = (size_t)in_sizes[3] * sizeof(unsigned short);

    if (ws_size >= weBytes) {
        unsigned short* WEb = (unsigned short*)d_ws;
        const int preBlocks = (nEnt + 8 * 4 - 1) / (8 * 4);   // 8 rows/wave
        we_kernel<<<preBlocks, 256, 0, stream>>>(entity_emb, W, WEb, nEnt);
        const int mainBlocks = nPairs;                        // 1 block/pair, 4 waves
        kgcn_main<<<mainBlocks, 256, 0, stream>>>(pairs, adj_entity, adj_relation,
                                                  WEb, relation_emb, user_emb,
                                                  W, b, out, nPairs);
    } else {
        const int nBlocks = (nPairs + 1) / 2;
        kgcn_fallback<<<nBlocks, 256, 0, stream>>>(pairs, adj_entity, adj_relation,
                                                   entity_emb, relation_emb, user_emb,
                                                   W, b, out, nPairs);
    }
}

// Round 2
// 128.687 us; speedup vs baseline: 1.2554x; 1.2554x over previous
//
#include <hip/hip_runtime.h>
#include <hip/hip_bf16.h>
#include <math.h>

#define DIM  64
#define KN   16
#define NREL 32

__device__ __forceinline__ float frcp(float x) { return __builtin_amdgcn_rcpf(x); }

__device__ __forceinline__ unsigned short f2bf(float f) {
    unsigned u = __float_as_uint(f);
    u = (u + 0x7fffu + ((u >> 16) & 1u)) >> 16;   // RNE
    return (unsigned short)u;
}
// bf16 pair packed in a dword: low ushort = even dim, high ushort = odd dim
__device__ __forceinline__ float bflo(unsigned v) { return __uint_as_float(v << 16); }
__device__ __forceinline__ float bfhi(unsigned v) { return __uint_as_float(v & 0xffff0000u); }

typedef __attribute__((ext_vector_type(8))) short bfrag;   // 8 bf16 (4 VGPRs)
typedef __attribute__((ext_vector_type(4))) float f32x4;   // MFMA accumulator

// ============================================================================
// Kernel 1 (R13): WE precompute as MFMA GEMM, transposed orientation
// D = W · E^T so that C/D lane layout gives each lane 4 CONSECUTIVE output
// dims (packed uint2 stores). Layouts per m89-verified mapping:
//   A (W):  lane holds A[row = lane&15][k = 8*(lane>>4)+i (+32*ks)]
//   B (E^T): lane holds B[k = 8*(lane>>4)+i (+32*ks)][col = lane&15]
//   D:      lane holds D[4*(lane>>4)+r][lane&15],  r = 0..3
// Identical k-indexing on A and B ⇒ any hw k-permutation cancels in the dot.
// 2 row-tiles (32 entity rows) per wave; no LDS.
// ============================================================================
__global__ __launch_bounds__(256, 2) void we_kernel_mfma(
    const float* __restrict__ entity_emb,
    const float* __restrict__ W,
    unsigned short* __restrict__ WEb,
    int nRows)
{
    const int tid  = threadIdx.x;
    const int wave = tid >> 6;
    const int lane = tid & 63;
    const int c = lane & 15;          // A-row (W row within d-tile) / B-col (entity within tile)
    const int g = lane >> 4;          // k-group: k = 8g + i (+32*ks)

    const int nTiles = (nRows + 15) >> 4;
    const int t0 = (blockIdx.x * 4 + wave) * 2;       // 2 tiles per wave
    if (t0 >= nTiles) return;

    // ---- W fragments: a[m][ks][i] = bf16(W[16m + c][8g + i + 32ks]) ----
    bfrag a[4][2];
    #pragma unroll
    for (int m = 0; m < 4; ++m) {
        #pragma unroll
        for (int ks = 0; ks < 2; ++ks) {
            const float4* ws = (const float4*)(W + (size_t)(16 * m + c) * DIM + 8 * g + 32 * ks);
            const float4 w0 = ws[0], w1 = ws[1];
            a[m][ks][0] = (short)f2bf(w0.x); a[m][ks][1] = (short)f2bf(w0.y);
            a[m][ks][2] = (short)f2bf(w0.z); a[m][ks][3] = (short)f2bf(w0.w);
            a[m][ks][4] = (short)f2bf(w1.x); a[m][ks][5] = (short)f2bf(w1.y);
            a[m][ks][6] = (short)f2bf(w1.z); a[m][ks][7] = (short)f2bf(w1.w);
        }
    }

    // ---- issue both tiles' E loads up front (8 dwordx4 in flight) ----
    float4 pe[2][4];
    #pragma unroll
    for (int j = 0; j < 2; ++j) {
        const int t = (t0 + j < nTiles) ? (t0 + j) : 0;
        int row = 16 * t + c;
        if (row >= nRows) row = nRows - 1;            // clamp; garbage never stored
        const float4* src = (const float4*)(entity_emb + (size_t)row * DIM + 8 * g);
        pe[j][0] = src[0];   // k = 8g .. 8g+3
        pe[j][1] = src[1];   // k = 8g+4 .. 8g+7
        pe[j][2] = src[8];   // k = 32+8g ..
        pe[j][3] = src[9];
    }

    #pragma unroll
    for (int j = 0; j < 2; ++j) {
        const int t = t0 + j;
        if (t >= nTiles) continue;

        bfrag b0, b1;
        b0[0] = (short)f2bf(pe[j][0].x); b0[1] = (short)f2bf(pe[j][0].y);
        b0[2] = (short)f2bf(pe[j][0].z); b0[3] = (short)f2bf(pe[j][0].w);
        b0[4] = (short)f2bf(pe[j][1].x); b0[5] = (short)f2bf(pe[j][1].y);
        b0[6] = (short)f2bf(pe[j][1].z); b0[7] = (short)f2bf(pe[j][1].w);
        b1[0] = (short)f2bf(pe[j][2].x); b1[1] = (short)f2bf(pe[j][2].y);
        b1[2] = (short)f2bf(pe[j][2].z); b1[3] = (short)f2bf(pe[j][2].w);
        b1[4] = (short)f2bf(pe[j][3].x); b1[5] = (short)f2bf(pe[j][3].y);
        b1[6] = (short)f2bf(pe[j][3].z); b1[7] = (short)f2bf(pe[j][3].w);

        f32x4 acc[4];
        #pragma unroll
        for (int m = 0; m < 4; ++m) {
            f32x4 z = {0.f, 0.f, 0.f, 0.f};
            z = __builtin_amdgcn_mfma_f32_16x16x32_bf16(a[m][0], b0, z, 0, 0, 0);
            z = __builtin_amdgcn_mfma_f32_16x16x32_bf16(a[m][1], b1, z, 0, 0, 0);
            acc[m] = z;
        }

        const int erow = 16 * t + c;                  // entity row this lane outputs
        if (erow < nRows) {
            #pragma unroll
            for (int m = 0; m < 4; ++m) {
                // lane owns dims d = 16m + 4g + r (r=0..3) of row erow
                const unsigned lo = (unsigned)f2bf(acc[m][0]) | ((unsigned)f2bf(acc[m][1]) << 16);
                const unsigned hi = (unsigned)f2bf(acc[m][2]) | ((unsigned)f2bf(acc[m][3]) << 16);
                *(uint2*)(WEb + (size_t)erow * DIM + 16 * m + 4 * g) = make_uint2(lo, hi);
            }
        }
    }
}

// ============================================================================
// Kernel 2: main — REVERTED to the verified R11 structure (1 wave/pair,
// 4 groups per wave in quarter-parallel, ~68 loads in flight per wave).
// R12's 4-wave split measured 48.8us vs R11's ~34.5us: per-wave MLP beats
// occupancy for this gather-latency-bound kernel.
// ============================================================================
__global__ __launch_bounds__(256, 4) void kgcn_main(
    const int* __restrict__ pairs,
    const int* __restrict__ adjE,
    const int* __restrict__ adjR,
    const unsigned short* __restrict__ WEb,
    const float* __restrict__ relation_emb,
    const float* __restrict__ user_emb,
    const float* __restrict__ W,
    const float* __restrict__ bias,
    float* __restrict__ out,
    int nPairs)
{
    __shared__ float ev1_s[4][KN * DIM];  // per-wave layer-0 outputs
    __shared__ float xb_s[4][DIM];        // per-wave matvec broadcast buffer

    const int tid  = threadIdx.x;
    const int wave = tid >> 6;
    const int lane = tid & 63;
    const int p    = blockIdx.x * 4 + wave;
    if (p >= nPairs) return;              // no barriers -> safe early-out

    float* ev1 = ev1_s[wave];
    float* xb  = xb_s[wave];

    const int qq = lane >> 4;             // quarter-wave id (0..3)
    const int c  = lane & 15;             // uint2 column within a WE row
    const int c4 = c * 4;                 // first owned dim

    const int user = pairs[2 * p + 0];
    const int item = pairs[2 * p + 1];

    const float4 b4 = *(const float4*)(bias + c4);
    const uint2* WEq = (const uint2*)WEb;   // row e starts at e*16 uint2

    // item adjacency row
    int rk0 = 0, e1 = 0;
    if (lane < KN) {
        rk0 = adjR[(size_t)item * KN + lane];
        e1  = adjE[(size_t)item * KN + lane];
    }

    // dot(u, rel_r) for all 32 relations: 2 lanes per relation
    float acc;
    {
        const int r = lane >> 1, hlf = lane & 1;
        const float4* rel4 = (const float4*)(relation_emb + r * DIM + hlf * 32);
        const float4* u4   = (const float4*)(user_emb + (size_t)user * DIM + hlf * 32);
        float a0 = 0.f, a1 = 0.f;
        #pragma unroll
        for (int j = 0; j < 8; j += 2) {
            float4 a = rel4[j],      b = u4[j];
            float4 cc = rel4[j + 1], d = u4[j + 1];
            a0 += a.x*b.x + a.y*b.y + a.z*b.z + a.w*b.w;
            a1 += cc.x*d.x + cc.y*d.y + cc.z*d.z + cc.w*d.w;
        }
        acc = a0 + a1;
        acc += __shfl_xor(acc, 1);
    }

    // ---- EARLY independent loads: hop-0 gather rows (item self + 4
    // neighbors per quarter) stay in flight through the whole hop-1 phase.
    const uint2 itemv = WEq[(size_t)item * 16 + c];
    uint2 h0v[4];
    #pragma unroll
    for (int k = 0; k < 4; ++k) {
        const int e = __shfl(e1, qq * 4 + k);
        h0v[k] = WEq[(size_t)(unsigned)e * 16 + c];
    }

    // ---- slot adjacency: ALL loads first, then the dependent softmaxes ----
    int rkA[4], ekA[4];
    #pragma unroll
    for (int s = 0; s < 4; ++s) {
        const int g = __shfl(e1, 4 * s + qq);
        rkA[s] = adjR[(size_t)(unsigned)g * KN + c];
        ekA[s] = adjE[(size_t)(unsigned)g * KN + c];
    }

    // softmax within 16-lane subgroups (4 independent groups per call)
    auto softmax16 = [&](float s) -> float {
        float mx = s;
        mx = fmaxf(mx, __shfl_xor(mx, 1));
        mx = fmaxf(mx, __shfl_xor(mx, 2));
        mx = fmaxf(mx, __shfl_xor(mx, 4));
        mx = fmaxf(mx, __shfl_xor(mx, 8));
        float e = __expf(s - mx);
        float ss = e;
        ss += __shfl_xor(ss, 1);
        ss += __shfl_xor(ss, 2);
        ss += __shfl_xor(ss, 4);
        ss += __shfl_xor(ss, 8);
        return e * frcp(ss);
    };

    float wA[4];
    #pragma unroll
    for (int s = 0; s < 4; ++s) wA[s] = softmax16(__shfl(acc, rkA[s] << 1));
    const float w0 = softmax16(__shfl(acc, rk0 << 1));

    // ---- layer 0, hop 1: 4 groups per outer iter (quarter qq owns group
    // 4s+qq); unroll 2 => two iterations' loads (34) pipeline together.
    #pragma unroll 2
    for (int s = 0; s < 4; ++s) {
        const int gm = 4 * s + qq;
        const int gs = __shfl(e1, gm);            // self row (per quarter)
        uint2 sv = WEq[(size_t)(unsigned)gs * 16 + c];
        float ax = b4.x + bflo(sv.x);
        float ay = b4.y + bfhi(sv.x);
        float az = b4.z + bflo(sv.y);
        float aw = b4.w + bfhi(sv.y);
        #pragma unroll
        for (int k = 0; k < KN; ++k) {
            const int   e = __shfl(ekA[s], qq * 16 + k);
            const float w = __shfl(wA[s],  qq * 16 + k);
            uint2 v = WEq[(size_t)(unsigned)e * 16 + c];
            ax += w * bflo(v.x);
            ay += w * bfhi(v.x);
            az += w * bflo(v.y);
            aw += w * bfhi(v.y);
        }
        *(float4*)&ev1[gm * DIM + c4] =
            make_float4(fmaxf(ax, 0.f), fmaxf(ay, 0.f), fmaxf(az, 0.f), fmaxf(aw, 0.f));
    }

    // ---- hop 0, layer 0: accumulate the preloaded rows (4/4/4/4 split).
    // Lanes c, c+16, c+32, c+48 own the SAME dims -> xor-16/32 combine aligns.
    float ax = 0.f, ay = 0.f, az = 0.f, aw = 0.f;
    #pragma unroll
    for (int k = 0; k < 4; ++k) {
        const float w = __shfl(w0, qq * 4 + k);
        ax += w * bflo(h0v[k].x);
        ay += w * bfhi(h0v[k].x);
        az += w * bflo(h0v[k].y);
        aw += w * bfhi(h0v[k].y);
    }
    ax += __shfl_xor(ax, 16); ay += __shfl_xor(ay, 16);
    az += __shfl_xor(az, 16); aw += __shfl_xor(aw, 16);
    ax += __shfl_xor(ax, 32); ay += __shfl_xor(ay, 32);
    az += __shfl_xor(az, 32); aw += __shfl_xor(aw, 32);
    ax += bflo(itemv.x) + b4.x;
    ay += bfhi(itemv.x) + b4.y;
    az += bflo(itemv.y) + b4.z;
    aw += bfhi(itemv.y) + b4.w;
    const float e0x = fmaxf(ax, 0.f), e0y = fmaxf(ay, 0.f);
    const float e0z = fmaxf(az, 0.f), e0w = fmaxf(aw, 0.f);

    // ---- layer 1 aggregate: x1 = e0 + sum_k w0_k * ev1_k (quarter-split)
    asm volatile("s_waitcnt lgkmcnt(0)" ::: "memory");  // ev1 writes done (wave-local)
    float sx = 0.f, sy = 0.f, sz = 0.f, sw = 0.f;
    #pragma unroll
    for (int k = 0; k < 4; ++k) {
        const int   kg = qq * 4 + k;
        const float w  = __shfl(w0, kg);
        float4 ev = *(const float4*)&ev1[kg * DIM + c4];
        sx += w * ev.x;
        sy += w * ev.y;
        sz += w * ev.z;
        sw += w * ev.w;
    }
    sx += __shfl_xor(sx, 16); sy += __shfl_xor(sy, 16);
    sz += __shfl_xor(sz, 16); sw += __shfl_xor(sw, 16);
    sx += __shfl_xor(sx, 32); sy += __shfl_xor(sy, 32);
    sz += __shfl_xor(sz, 32); sw += __shfl_xor(sw, 32);

    // ---- the ONE real matvec: h1 = W x1 + b, via LDS broadcast ----
    asm volatile("s_waitcnt lgkmcnt(0)" ::: "memory");
    if (qq == 0)
        *(float4*)&xb[c4] = make_float4(e0x + sx, e0y + sy, e0z + sz, e0w + sw);
    asm volatile("s_waitcnt lgkmcnt(0)" ::: "memory");
    float h0 = bias[lane], h1 = 0.f, h2 = 0.f, h3 = 0.f;
    {
        const float4* Wl  = (const float4*)(W + lane * DIM);
        const float4* xv4 = (const float4*)xb;
        #pragma unroll
        for (int j = 0; j < 16; j += 4) {
            float4 w0v = Wl[j],   x0v = xv4[j];
            float4 w1v = Wl[j+1], x1v = xv4[j+1];
            float4 w2v = Wl[j+2], x2v = xv4[j+2];
            float4 w3v = Wl[j+3], x3v = xv4[j+3];
            h0 += w0v.x*x0v.x + w0v.y*x0v.y + w0v.z*x0v.z + w0v.w*x0v.w;
            h1 += w1v.x*x1v.x + w1v.y*x1v.y + w1v.z*x1v.z + w1v.w*x1v.w;
            h2 += w2v.x*x2v.x + w2v.y*x2v.y + w2v.z*x2v.z + w2v.w*x2v.w;
            h3 += w3v.x*x3v.x + w3v.y*x3v.y + w3v.z*x3v.z + w3v.w*x3v.w;
        }
    }
    const float itemf = tanhf((h0 + h1) + (h2 + h3));

    float d = user_emb[(size_t)user * DIM + lane] * itemf;
    d += __shfl_xor(d, 1);
    d += __shfl_xor(d, 2);
    d += __shfl_xor(d, 4);
    d += __shfl_xor(d, 8);
    d += __shfl_xor(d, 16);
    d += __shfl_xor(d, 32);
    if (lane == 0) out[p] = 1.f / (1.f + expf(-d));
}

// ============================================================================
// Fallback (verified R5 kernel) in case ws_size < WE table size.
// ============================================================================
__global__ __launch_bounds__(256, 4) void kgcn_fallback(
    const int* __restrict__ pairs, const int* __restrict__ adj_entity,
    const int* __restrict__ adj_relation, const float* __restrict__ entity_emb,
    const float* __restrict__ relation_emb, const float* __restrict__ user_emb,
    const float* __restrict__ W, const float* __restrict__ bias,
    float* __restrict__ out, int nPairs)
{
    __shared__ float ev1_s[2][KN * DIM];
    __shared__ float xb_s[4][DIM];
    const int tid = threadIdx.x, wave = tid >> 6, lane = tid & 63;
    const int q = wave >> 1, half = wave & 1;
    int p = blockIdx.x * 2 + q;
    if (p >= nPairs) p = nPairs - 1;
    float* ev1 = ev1_s[q]; float* xb = xb_s[wave];
    const int user = pairs[2 * p + 0], item = pairs[2 * p + 1];
    const float bval = bias[lane];
    const float* emb_l = entity_emb + lane;
    const float4* W4 = (const float4*)(W + lane * DIM);
    int rk0 = 0, e1 = 0;
    if (lane < KN) {
        rk0 = adj_relation[(size_t)item * KN + lane];
        e1  = adj_entity[(size_t)item * KN + lane];
    }
    float acc;
    {
        const int r = lane >> 1, hlf = lane & 1;
        const float4* rel4 = (const float4*)(relation_emb + r * DIM + hlf * 32);
        const float4* u4 = (const float4*)(user_emb + (size_t)user * DIM + hlf * 32);
        float a0 = 0.f, a1 = 0.f;
        #pragma unroll
        for (int j = 0; j < 8; j += 2) {
            float4 a = rel4[j], b = u4[j], c = rel4[j+1], d = u4[j+1];
            a0 += a.x*b.x + a.y*b.y + a.z*b.z + a.w*b.w;
            a1 += c.x*d.x + c.y*d.y + c.z*d.z + c.w*d.w;
        }
        acc = a0 + a1; acc += __shfl_xor(acc, 1);
    }
    auto softmax16 = [&](float s) -> float {
        float mx = s;
        mx = fmaxf(mx, __shfl_xor(mx, 1)); mx = fmaxf(mx, __shfl_xor(mx, 2));
        mx = fmaxf(mx, __shfl_xor(mx, 4)); mx = fmaxf(mx, __shfl_xor(mx, 8));
        float e = __expf(s - mx);
        float ss = e;
        ss += __shfl_xor(ss, 1); ss += __shfl_xor(ss, 2);
        ss += __shfl_xor(ss, 4); ss += __shfl_xor(ss, 8);
        return e * frcp(ss);
    };
    auto matvec = [&](float xv) -> float {
        asm volatile("s_waitcnt lgkmcnt(0)" ::: "memory");
        xb[lane] = xv;
        asm volatile("s_waitcnt lgkmcnt(0)" ::: "memory");
        float h0 = bval, h1 = 0.f, h2 = 0.f, h3 = 0.f;
        const float4* xv4 = (const float4*)xb;
        #pragma unroll
        for (int j = 0; j < 16; j += 4) {
            float4 w0 = W4[j], x0 = xv4[j], w1 = W4[j+1], x1 = xv4[j+1];
            float4 w2 = W4[j+2], x2 = xv4[j+2], w3 = W4[j+3], x3 = xv4[j+3];
            h0 += w0.x*x0.x + w0.y*x0.y + w0.z*x0.z + w0.w*x0.w;
            h1 += w1.x*x1.x + w1.y*x1.y + w1.z*x1.z + w1.w*x1.w;
            h2 += w2.x*x2.x + w2.y*x2.y + w2.z*x2.z + w2.w*x2.w;
            h3 += w3.x*x3.x + w3.y*x3.y + w3.z*x3.z + w3.w*x3.w;
        }
        return (h0 + h1) + (h2 + h3);
    };
    auto gather = [&](int self, int ek, float w) -> float {
        float xa = emb_l[(size_t)(unsigned)self * DIM], xc = 0.f;
        #pragma unroll
        for (int k = 0; k < KN; k += 2) {
            const int e0i = __shfl(ek, k); const float f0 = __shfl(w, k);
            const int e1i = __shfl(ek, k + 1); const float f1 = __shfl(w, k + 1);
            xa += f0 * emb_l[(size_t)(unsigned)e0i * DIM];
            xc += f1 * emb_l[(size_t)(unsigned)e1i * DIM];
        }
        return xa + xc;
    };
    int rk_n = 0, ek_n = 0;
    {
        const int g0 = __shfl(e1, half * 8);
        if (lane < KN) {
            rk_n = adj_relation[(size_t)(unsigned)g0 * KN + lane];
            ek_n = adj_entity[(size_t)(unsigned)g0 * KN + lane];
        }
    }
    #pragma unroll 1
    for (int mi = 0; mi < 8; ++mi) {
        const int m = half * 8 + mi;
        const int g = __shfl(e1, m);
        const int rk = rk_n, ek = ek_n;
        if (mi + 1 < 8) {
            const int gn = __shfl(e1, m + 1);
            if (lane < KN) {
                rk_n = adj_relation[(size_t)(unsigned)gn * KN + lane];
                ek_n = adj_entity[(size_t)(unsigned)gn * KN + lane];
            }
        }
        const float w = softmax16(__shfl(acc, rk << 1));
        const float x = gather(g, ek, w);
        ev1[m * DIM + lane] = fmaxf(matvec(x), 0.f);
    }
    __syncthreads();
    if (half != 0) return;
    const float w0 = softmax16(__shfl(acc, rk0 << 1));
    const float x0 = gather(item, e1, w0);
    const float e0 = fmaxf(matvec(x0), 0.f);
    float xa = e0, xc = 0.f;
    #pragma unroll
    for (int k = 0; k < KN; k += 2) {
        xa += __shfl(w0, k) * ev1[k * DIM + lane];
        xc += __shfl(w0, k + 1) * ev1[(k + 1) * DIM + lane];
    }
    const float itemf = tanhf(matvec(xa + xc));
    float d = user_emb[(size_t)user * DIM + lane] * itemf;
    d += __shfl_xor(d, 1); d += __shfl_xor(d, 2); d += __shfl_xor(d, 4);
    d += __shfl_xor(d, 8); d += __shfl_xor(d, 16); d += __shfl_xor(d, 32);
    if (lane == 0) out[p] = 1.f / (1.f + expf(-d));
}

extern "C" void kernel_launch(void* const* d_in, const int* in_sizes, int n_in,
                              void* d_out, int out_size, void* d_ws, size_t ws_size,
                              hipStream_t stream) {
    const int*   pairs        = (const int*)d_in[0];
    const int*   adj_entity   = (const int*)d_in[1];
    const int*   adj_relation = (const int*)d_in[2];
    const float* entity_emb   = (const float*)d_in[3];
    const float* relation_emb = (const float*)d_in[4];
    const float* user_emb     = (const float*)d_in[5];
    const float* W            = (const float*)d_in[6];
    const float* b            = (const float*)d_in[7];
    float* out = (float*)d_out;

    const int nPairs = in_sizes[0] / 2;          // pairs is (B, 2)
    const int nEnt   = in_sizes[3] / DIM;        // entity count
    const size_t weBytes = (size_t)in_sizes[3] * sizeof(unsigned short);

    if (ws_size >= weBytes) {
        unsigned short* WEb = (unsigned short*)d_ws;
        const int nTiles = (nEnt + 15) >> 4;
        const int preBlocks = (nTiles + 7) / 8;   // 2 tiles/wave, 4 waves/block
        we_kernel_mfma<<<preBlocks, 256, 0, stream>>>(entity_emb, W, WEb, nEnt);
        const int mainBlocks = (nPairs + 3) / 4;  // 1 wave/pair (R11 structure)
        kgcn_main<<<mainBlocks, 256, 0, stream>>>(pairs, adj_entity, adj_relation,
                                                  WEb, relation_emb, user_emb,
                                                  W, b, out, nPairs);
    } else {
        const int nBlocks = (nPairs + 1) / 2;
        kgcn_fallback<<<nBlocks, 256, 0, stream>>>(pairs, adj_entity, adj_relation,
                                                   entity_emb, relation_emb, user_emb,
                                                   W, b, out, nPairs);
    }
}

// Round 3
// 128.187 us; speedup vs baseline: 1.2603x; 1.0039x over previous
//
#include <hip/hip_runtime.h>
#include <hip/hip_bf16.h>
#include <math.h>

#define DIM  64
#define KN   16
#define NREL 32

__device__ __forceinline__ float frcp(float x) { return __builtin_amdgcn_rcpf(x); }

__device__ __forceinline__ unsigned short f2bf(float f) {
    unsigned u = __float_as_uint(f);
    u = (u + 0x7fffu + ((u >> 16) & 1u)) >> 16;   // RNE
    return (unsigned short)u;
}
// bf16 pair packed in a dword: low ushort = even dim, high ushort = odd dim
__device__ __forceinline__ float bflo(unsigned v) { return __uint_as_float(v << 16); }
__device__ __forceinline__ float bfhi(unsigned v) { return __uint_as_float(v & 0xffff0000u); }

typedef __attribute__((ext_vector_type(8))) short bfrag;   // 8 bf16 (4 VGPRs)
typedef __attribute__((ext_vector_type(4))) float f32x4;   // MFMA accumulator

// ============================================================================
// Kernel 1 (R13, verified): WE precompute as MFMA GEMM, D = W · E^T.
// ============================================================================
__global__ __launch_bounds__(256, 2) void we_kernel_mfma(
    const float* __restrict__ entity_emb,
    const float* __restrict__ W,
    unsigned short* __restrict__ WEb,
    int nRows)
{
    const int tid  = threadIdx.x;
    const int wave = tid >> 6;
    const int lane = tid & 63;
    const int c = lane & 15;          // A-row (W row within d-tile) / B-col (entity within tile)
    const int g = lane >> 4;          // k-group: k = 8g + i (+32*ks)

    const int nTiles = (nRows + 15) >> 4;
    const int t0 = (blockIdx.x * 4 + wave) * 2;       // 2 tiles per wave
    if (t0 >= nTiles) return;

    // ---- W fragments: a[m][ks][i] = bf16(W[16m + c][8g + i + 32ks]) ----
    bfrag a[4][2];
    #pragma unroll
    for (int m = 0; m < 4; ++m) {
        #pragma unroll
        for (int ks = 0; ks < 2; ++ks) {
            const float4* ws = (const float4*)(W + (size_t)(16 * m + c) * DIM + 8 * g + 32 * ks);
            const float4 w0 = ws[0], w1 = ws[1];
            a[m][ks][0] = (short)f2bf(w0.x); a[m][ks][1] = (short)f2bf(w0.y);
            a[m][ks][2] = (short)f2bf(w0.z); a[m][ks][3] = (short)f2bf(w0.w);
            a[m][ks][4] = (short)f2bf(w1.x); a[m][ks][5] = (short)f2bf(w1.y);
            a[m][ks][6] = (short)f2bf(w1.z); a[m][ks][7] = (short)f2bf(w1.w);
        }
    }

    // ---- issue both tiles' E loads up front (8 dwordx4 in flight) ----
    float4 pe[2][4];
    #pragma unroll
    for (int j = 0; j < 2; ++j) {
        const int t = (t0 + j < nTiles) ? (t0 + j) : 0;
        int row = 16 * t + c;
        if (row >= nRows) row = nRows - 1;            // clamp; garbage never stored
        const float4* src = (const float4*)(entity_emb + (size_t)row * DIM + 8 * g);
        pe[j][0] = src[0];   // k = 8g .. 8g+3
        pe[j][1] = src[1];   // k = 8g+4 .. 8g+7
        pe[j][2] = src[8];   // k = 32+8g ..
        pe[j][3] = src[9];
    }

    #pragma unroll
    for (int j = 0; j < 2; ++j) {
        const int t = t0 + j;
        if (t >= nTiles) continue;

        bfrag b0, b1;
        b0[0] = (short)f2bf(pe[j][0].x); b0[1] = (short)f2bf(pe[j][0].y);
        b0[2] = (short)f2bf(pe[j][0].z); b0[3] = (short)f2bf(pe[j][0].w);
        b0[4] = (short)f2bf(pe[j][1].x); b0[5] = (short)f2bf(pe[j][1].y);
        b0[6] = (short)f2bf(pe[j][1].z); b0[7] = (short)f2bf(pe[j][1].w);
        b1[0] = (short)f2bf(pe[j][2].x); b1[1] = (short)f2bf(pe[j][2].y);
        b1[2] = (short)f2bf(pe[j][2].z); b1[3] = (short)f2bf(pe[j][2].w);
        b1[4] = (short)f2bf(pe[j][3].x); b1[5] = (short)f2bf(pe[j][3].y);
        b1[6] = (short)f2bf(pe[j][3].z); b1[7] = (short)f2bf(pe[j][3].w);

        f32x4 acc[4];
        #pragma unroll
        for (int m = 0; m < 4; ++m) {
            f32x4 z = {0.f, 0.f, 0.f, 0.f};
            z = __builtin_amdgcn_mfma_f32_16x16x32_bf16(a[m][0], b0, z, 0, 0, 0);
            z = __builtin_amdgcn_mfma_f32_16x16x32_bf16(a[m][1], b1, z, 0, 0, 0);
            acc[m] = z;
        }

        const int erow = 16 * t + c;                  // entity row this lane outputs
        if (erow < nRows) {
            #pragma unroll
            for (int m = 0; m < 4; ++m) {
                // lane owns dims d = 16m + 4g + r (r=0..3) of row erow
                const unsigned lo = (unsigned)f2bf(acc[m][0]) | ((unsigned)f2bf(acc[m][1]) << 16);
                const unsigned hi = (unsigned)f2bf(acc[m][2]) | ((unsigned)f2bf(acc[m][3]) << 16);
                *(uint2*)(WEb + (size_t)erow * DIM + 16 * m + 4 * g) = make_uint2(lo, hi);
            }
        }
    }
}

// ============================================================================
// Kernel 2 (R14): R11 structure + T14 issue-all-then-consume. All hop-1
// gather addresses depend only on ekA (not weights), so slots 0..2 (51 uint2)
// + all self rows are ISSUED before any softmax runs; the 5 serial-shfl
// softmaxes execute under the gather flight; slot 3's neighbors issue right
// after slot 0's consumption frees registers. launch_bounds(256,3): VGPR cap
// 170 for the ~150-reg in-flight peak, 12 waves/CU.
// ============================================================================
__global__ __launch_bounds__(256, 3) void kgcn_main(
    const int* __restrict__ pairs,
    const int* __restrict__ adjE,
    const int* __restrict__ adjR,
    const unsigned short* __restrict__ WEb,
    const float* __restrict__ relation_emb,
    const float* __restrict__ user_emb,
    const float* __restrict__ W,
    const float* __restrict__ bias,
    float* __restrict__ out,
    int nPairs)
{
    __shared__ float ev1_s[4][KN * DIM];  // per-wave layer-0 outputs
    __shared__ float xb_s[4][DIM];        // per-wave matvec broadcast buffer

    const int tid  = threadIdx.x;
    const int wave = tid >> 6;
    const int lane = tid & 63;
    const int p    = blockIdx.x * 4 + wave;
    if (p >= nPairs) return;              // no barriers -> safe early-out

    float* ev1 = ev1_s[wave];
    float* xb  = xb_s[wave];

    const int qq = lane >> 4;             // quarter-wave id (0..3)
    const int c  = lane & 15;             // uint2 column within a WE row
    const int c4 = c * 4;                 // first owned dim

    const int user = pairs[2 * p + 0];
    const int item = pairs[2 * p + 1];

    const float4 b4 = *(const float4*)(bias + c4);
    const uint2* WEq = (const uint2*)WEb;   // row e starts at e*16 uint2

    // ---- chase root: item adjacency row (oldest loads in flight) ----
    int rk0 = 0, e1 = 0;
    if (lane < KN) {
        rk0 = adjR[(size_t)item * KN + lane];
        e1  = adjE[(size_t)item * KN + lane];
    }

    // ---- independent: user/relation rows into regs (fly during e1 wait) ----
    float4 rr[8], ur[8];
    {
        const int r = lane >> 1, hlf = lane & 1;
        const float4* rel4 = (const float4*)(relation_emb + r * DIM + hlf * 32);
        const float4* u4   = (const float4*)(user_emb + (size_t)user * DIM + hlf * 32);
        #pragma unroll
        for (int j = 0; j < 8; ++j) { rr[j] = rel4[j]; ur[j] = u4[j]; }
    }

    // ---- e1 arrival gates: hop-0 rows + slot adjacency (issue ASAP) ----
    const uint2 itemv = WEq[(size_t)item * 16 + c];
    uint2 h0v[4];
    #pragma unroll
    for (int k = 0; k < 4; ++k) {
        const int e = __shfl(e1, qq * 4 + k);
        h0v[k] = WEq[(size_t)(unsigned)e * 16 + c];
    }
    int rkA[4], ekA[4], gsA[4];
    #pragma unroll
    for (int s = 0; s < 4; ++s) {
        gsA[s] = __shfl(e1, 4 * s + qq);
        rkA[s] = adjR[(size_t)(unsigned)gsA[s] * KN + c];
        ekA[s] = adjE[(size_t)(unsigned)gsA[s] * KN + c];
    }

    // ---- dot(u, rel_r): consume the reg-staged rows (adjacency in flight) ----
    float acc;
    {
        float a0 = 0.f, a1 = 0.f;
        #pragma unroll
        for (int j = 0; j < 8; j += 2) {
            float4 a = rr[j],     b = ur[j];
            float4 cc = rr[j+1],  d = ur[j+1];
            a0 += a.x*b.x + a.y*b.y + a.z*b.z + a.w*b.w;
            a1 += cc.x*d.x + cc.y*d.y + cc.z*d.z + cc.w*d.w;
        }
        acc = a0 + a1;
        acc += __shfl_xor(acc, 1);
    }

    // ---- ISSUE hop-1 gathers for slots 0..2 + ALL self rows (addresses
    // need only ekA). 55 uint2 loads go into flight before any softmax. ----
    uint2 svA[4];
    uint2 nvA[3][KN];
    #pragma unroll
    for (int s = 0; s < 3; ++s) {
        svA[s] = WEq[(size_t)(unsigned)gsA[s] * 16 + c];
        #pragma unroll
        for (int k = 0; k < KN; ++k) {
            const int e = __shfl(ekA[s], qq * 16 + k);
            nvA[s][k] = WEq[(size_t)(unsigned)e * 16 + c];
        }
    }
    svA[3] = WEq[(size_t)(unsigned)gsA[3] * 16 + c];

    // softmax within 16-lane subgroups (4 independent groups per call)
    auto softmax16 = [&](float s) -> float {
        float mx = s;
        mx = fmaxf(mx, __shfl_xor(mx, 1));
        mx = fmaxf(mx, __shfl_xor(mx, 2));
        mx = fmaxf(mx, __shfl_xor(mx, 4));
        mx = fmaxf(mx, __shfl_xor(mx, 8));
        float e = __expf(s - mx);
        float ss = e;
        ss += __shfl_xor(ss, 1);
        ss += __shfl_xor(ss, 2);
        ss += __shfl_xor(ss, 4);
        ss += __shfl_xor(ss, 8);
        return e * frcp(ss);
    };

    // ---- softmaxes run UNDER the gather flight ----
    float wA[4];
    #pragma unroll
    for (int s = 0; s < 4; ++s) wA[s] = softmax16(__shfl(acc, rkA[s] << 1));
    const float w0 = softmax16(__shfl(acc, rk0 << 1));

    // ---- consume slot 0 (frees 34 regs), then issue slot 3's neighbors ----
    {
        float ax = b4.x + bflo(svA[0].x);
        float ay = b4.y + bfhi(svA[0].x);
        float az = b4.z + bflo(svA[0].y);
        float aw = b4.w + bfhi(svA[0].y);
        #pragma unroll
        for (int k = 0; k < KN; ++k) {
            const float w = __shfl(wA[0], qq * 16 + k);
            uint2 v = nvA[0][k];
            ax += w * bflo(v.x);
            ay += w * bfhi(v.x);
            az += w * bflo(v.y);
            aw += w * bfhi(v.y);
        }
        *(float4*)&ev1[qq * DIM + c4] =
            make_float4(fmaxf(ax, 0.f), fmaxf(ay, 0.f), fmaxf(az, 0.f), fmaxf(aw, 0.f));
    }
    uint2 nv3[KN];
    #pragma unroll
    for (int k = 0; k < KN; ++k) {
        const int e = __shfl(ekA[3], qq * 16 + k);
        nv3[k] = WEq[(size_t)(unsigned)e * 16 + c];
    }
    #pragma unroll
    for (int s = 1; s < 3; ++s) {
        float ax = b4.x + bflo(svA[s].x);
        float ay = b4.y + bfhi(svA[s].x);
        float az = b4.z + bflo(svA[s].y);
        float aw = b4.w + bfhi(svA[s].y);
        #pragma unroll
        for (int k = 0; k < KN; ++k) {
            const float w = __shfl(wA[s], qq * 16 + k);
            uint2 v = nvA[s][k];
            ax += w * bflo(v.x);
            ay += w * bfhi(v.x);
            az += w * bflo(v.y);
            aw += w * bfhi(v.y);
        }
        *(float4*)&ev1[(4 * s + qq) * DIM + c4] =
            make_float4(fmaxf(ax, 0.f), fmaxf(ay, 0.f), fmaxf(az, 0.f), fmaxf(aw, 0.f));
    }
    {
        float ax = b4.x + bflo(svA[3].x);
        float ay = b4.y + bfhi(svA[3].x);
        float az = b4.z + bflo(svA[3].y);
        float aw = b4.w + bfhi(svA[3].y);
        #pragma unroll
        for (int k = 0; k < KN; ++k) {
            const float w = __shfl(wA[3], qq * 16 + k);
            uint2 v = nv3[k];
            ax += w * bflo(v.x);
            ay += w * bfhi(v.x);
            az += w * bflo(v.y);
            aw += w * bfhi(v.y);
        }
        *(float4*)&ev1[(12 + qq) * DIM + c4] =
            make_float4(fmaxf(ax, 0.f), fmaxf(ay, 0.f), fmaxf(az, 0.f), fmaxf(aw, 0.f));
    }

    // ---- hop 0, layer 0: accumulate the preloaded rows (4/4/4/4 split).
    // Lanes c, c+16, c+32, c+48 own the SAME dims -> xor-16/32 combine aligns.
    float ax = 0.f, ay = 0.f, az = 0.f, aw = 0.f;
    #pragma unroll
    for (int k = 0; k < 4; ++k) {
        const float w = __shfl(w0, qq * 4 + k);
        ax += w * bflo(h0v[k].x);
        ay += w * bfhi(h0v[k].x);
        az += w * bflo(h0v[k].y);
        aw += w * bfhi(h0v[k].y);
    }
    ax += __shfl_xor(ax, 16); ay += __shfl_xor(ay, 16);
    az += __shfl_xor(az, 16); aw += __shfl_xor(aw, 16);
    ax += __shfl_xor(ax, 32); ay += __shfl_xor(ay, 32);
    az += __shfl_xor(az, 32); aw += __shfl_xor(aw, 32);
    ax += bflo(itemv.x) + b4.x;
    ay += bfhi(itemv.x) + b4.y;
    az += bflo(itemv.y) + b4.z;
    aw += bfhi(itemv.y) + b4.w;
    const float e0x = fmaxf(ax, 0.f), e0y = fmaxf(ay, 0.f);
    const float e0z = fmaxf(az, 0.f), e0w = fmaxf(aw, 0.f);

    // ---- layer 1 aggregate: x1 = e0 + sum_k w0_k * ev1_k (quarter-split)
    asm volatile("s_waitcnt lgkmcnt(0)" ::: "memory");  // ev1 writes done (wave-local)
    float sx = 0.f, sy = 0.f, sz = 0.f, sw = 0.f;
    #pragma unroll
    for (int k = 0; k < 4; ++k) {
        const int   kg = qq * 4 + k;
        const float w  = __shfl(w0, kg);
        float4 ev = *(const float4*)&ev1[kg * DIM + c4];
        sx += w * ev.x;
        sy += w * ev.y;
        sz += w * ev.z;
        sw += w * ev.w;
    }
    sx += __shfl_xor(sx, 16); sy += __shfl_xor(sy, 16);
    sz += __shfl_xor(sz, 16); sw += __shfl_xor(sw, 16);
    sx += __shfl_xor(sx, 32); sy += __shfl_xor(sy, 32);
    sz += __shfl_xor(sz, 32); sw += __shfl_xor(sw, 32);

    // ---- the ONE real matvec: h1 = W x1 + b, via LDS broadcast ----
    asm volatile("s_waitcnt lgkmcnt(0)" ::: "memory");
    if (qq == 0)
        *(float4*)&xb[c4] = make_float4(e0x + sx, e0y + sy, e0z + sz, e0w + sw);
    asm volatile("s_waitcnt lgkmcnt(0)" ::: "memory");
    float h0 = bias[lane], h1 = 0.f, h2 = 0.f, h3 = 0.f;
    {
        const float4* Wl  = (const float4*)(W + lane * DIM);
        const float4* xv4 = (const float4*)xb;
        #pragma unroll
        for (int j = 0; j < 16; j += 4) {
            float4 w0v = Wl[j],   x0v = xv4[j];
            float4 w1v = Wl[j+1], x1v = xv4[j+1];
            float4 w2v = Wl[j+2], x2v = xv4[j+2];
            float4 w3v = Wl[j+3], x3v = xv4[j+3];
            h0 += w0v.x*x0v.x + w0v.y*x0v.y + w0v.z*x0v.z + w0v.w*x0v.w;
            h1 += w1v.x*x1v.x + w1v.y*x1v.y + w1v.z*x1v.z + w1v.w*x1v.w;
            h2 += w2v.x*x2v.x + w2v.y*x2v.y + w2v.z*x2v.z + w2v.w*x2v.w;
            h3 += w3v.x*x3v.x + w3v.y*x3v.y + w3v.z*x3v.z + w3v.w*x3v.w;
        }
    }
    const float itemf = tanhf((h0 + h1) + (h2 + h3));

    float d = user_emb[(size_t)user * DIM + lane] * itemf;
    d += __shfl_xor(d, 1);
    d += __shfl_xor(d, 2);
    d += __shfl_xor(d, 4);
    d += __shfl_xor(d, 8);
    d += __shfl_xor(d, 16);
    d += __shfl_xor(d, 32);
    if (lane == 0) out[p] = 1.f / (1.f + expf(-d));
}

// ============================================================================
// Fallback (verified R5 kernel) in case ws_size < WE table size.
// ============================================================================
__global__ __launch_bounds__(256, 4) void kgcn_fallback(
    const int* __restrict__ pairs, const int* __restrict__ adj_entity,
    const int* __restrict__ adj_relation, const float* __restrict__ entity_emb,
    const float* __restrict__ relation_emb, const float* __restrict__ user_emb,
    const float* __restrict__ W, const float* __restrict__ bias,
    float* __restrict__ out, int nPairs)
{
    __shared__ float ev1_s[2][KN * DIM];
    __shared__ float xb_s[4][DIM];
    const int tid = threadIdx.x, wave = tid >> 6, lane = tid & 63;
    const int q = wave >> 1, half = wave & 1;
    int p = blockIdx.x * 2 + q;
    if (p >= nPairs) p = nPairs - 1;
    float* ev1 = ev1_s[q]; float* xb = xb_s[wave];
    const int user = pairs[2 * p + 0], item = pairs[2 * p + 1];
    const float bval = bias[lane];
    const float* emb_l = entity_emb + lane;
    const float4* W4 = (const float4*)(W + lane * DIM);
    int rk0 = 0, e1 = 0;
    if (lane < KN) {
        rk0 = adj_relation[(size_t)item * KN + lane];
        e1  = adj_entity[(size_t)item * KN + lane];
    }
    float acc;
    {
        const int r = lane >> 1, hlf = lane & 1;
        const float4* rel4 = (const float4*)(relation_emb + r * DIM + hlf * 32);
        const float4* u4 = (const float4*)(user_emb + (size_t)user * DIM + hlf * 32);
        float a0 = 0.f, a1 = 0.f;
        #pragma unroll
        for (int j = 0; j < 8; j += 2) {
            float4 a = rel4[j], b = u4[j], c = rel4[j+1], d = u4[j+1];
            a0 += a.x*b.x + a.y*b.y + a.z*b.z + a.w*b.w;
            a1 += c.x*d.x + c.y*d.y + c.z*d.z + c.w*d.w;
        }
        acc = a0 + a1; acc += __shfl_xor(acc, 1);
    }
    auto softmax16 = [&](float s) -> float {
        float mx = s;
        mx = fmaxf(mx, __shfl_xor(mx, 1)); mx = fmaxf(mx, __shfl_xor(mx, 2));
        mx = fmaxf(mx, __shfl_xor(mx, 4)); mx = fmaxf(mx, __shfl_xor(mx, 8));
        float e = __expf(s - mx);
        float ss = e;
        ss += __shfl_xor(ss, 1); ss += __shfl_xor(ss, 2);
        ss += __shfl_xor(ss, 4); ss += __shfl_xor(ss, 8);
        return e * frcp(ss);
    };
    auto matvec = [&](float xv) -> float {
        asm volatile("s_waitcnt lgkmcnt(0)" ::: "memory");
        xb[lane] = xv;
        asm volatile("s_waitcnt lgkmcnt(0)" ::: "memory");
        float h0 = bval, h1 = 0.f, h2 = 0.f, h3 = 0.f;
        const float4* xv4 = (const float4*)xb;
        #pragma unroll
        for (int j = 0; j < 16; j += 4) {
            float4 w0 = W4[j], x0 = xv4[j], w1 = W4[j+1], x1 = xv4[j+1];
            float4 w2 = W4[j+2], x2 = xv4[j+2], w3 = W4[j+3], x3 = xv4[j+3];
            h0 += w0.x*x0.x + w0.y*x0.y + w0.z*x0.z + w0.w*x0.w;
            h1 += w1.x*x1.x + w1.y*x1.y + w1.z*x1.z + w1.w*x1.w;
            h2 += w2.x*x2.x + w2.y*x2.y + w2.z*x2.z + w2.w*x2.w;
            h3 += w3.x*x3.x + w3.y*x3.y + w3.z*x3.z + w3.w*x3.w;
        }
        return (h0 + h1) + (h2 + h3);
    };
    auto gather = [&](int self, int ek, float w) -> float {
        float xa = emb_l[(size_t)(unsigned)self * DIM], xc = 0.f;
        #pragma unroll
        for (int k = 0; k < KN; k += 2) {
            const int e0i = __shfl(ek, k); const float f0 = __shfl(w, k);
            const int e1i = __shfl(ek, k + 1); const float f1 = __shfl(w, k + 1);
            xa += f0 * emb_l[(size_t)(unsigned)e0i * DIM];
            xc += f1 * emb_l[(size_t)(unsigned)e1i * DIM];
        }
        return xa + xc;
    };
    int rk_n = 0, ek_n = 0;
    {
        const int g0 = __shfl(e1, half * 8);
        if (lane < KN) {
            rk_n = adj_relation[(size_t)(unsigned)g0 * KN + lane];
            ek_n = adj_entity[(size_t)(unsigned)g0 * KN + lane];
        }
    }
    #pragma unroll 1
    for (int mi = 0; mi < 8; ++mi) {
        const int m = half * 8 + mi;
        const int g = __shfl(e1, m);
        const int rk = rk_n, ek = ek_n;
        if (mi + 1 < 8) {
            const int gn = __shfl(e1, m + 1);
            if (lane < KN) {
                rk_n = adj_relation[(size_t)(unsigned)gn * KN + lane];
                ek_n = adj_entity[(size_t)(unsigned)gn * KN + lane];
            }
        }
        const float w = softmax16(__shfl(acc, rk << 1));
        const float x = gather(g, ek, w);
        ev1[m * DIM + lane] = fmaxf(matvec(x), 0.f);
    }
    __syncthreads();
    if (half != 0) return;
    const float w0 = softmax16(__shfl(acc, rk0 << 1));
    const float x0 = gather(item, e1, w0);
    const float e0 = fmaxf(matvec(x0), 0.f);
    float xa = e0, xc = 0.f;
    #pragma unroll
    for (int k = 0; k < KN; k += 2) {
        xa += __shfl(w0, k) * ev1[k * DIM + lane];
        xc += __shfl(w0, k + 1) * ev1[(k + 1) * DIM + lane];
    }
    const float itemf = tanhf(matvec(xa + xc));
    float d = user_emb[(size_t)user * DIM + lane] * itemf;
    d += __shfl_xor(d, 1); d += __shfl_xor(d, 2); d += __shfl_xor(d, 4);
    d += __shfl_xor(d, 8); d += __shfl_xor(d, 16); d += __shfl_xor(d, 32);
    if (lane == 0) out[p] = 1.f / (1.f + expf(-d));
}

extern "C" void kernel_launch(void* const* d_in, const int* in_sizes, int n_in,
                              void* d_out, int out_size, void* d_ws, size_t ws_size,
                              hipStream_t stream) {
    const int*   pairs        = (const int*)d_in[0];
    const int*   adj_entity   = (const int*)d_in[1];
    const int*   adj_relation = (const int*)d_in[2];
    const float* entity_emb   = (const float*)d_in[3];
    const float* relation_emb = (const float*)d_in[4];
    const float* user_emb     = (const float*)d_in[5];
    const float* W            = (const float*)d_in[6];
    const float* b            = (const float*)d_in[7];
    float* out = (float*)d_out;

    const int nPairs = in_sizes[0] / 2;          // pairs is (B, 2)
    const int nEnt   = in_sizes[3] / DIM;        // entity count
    const size_t weBytes = (size_t)in_sizes[3] * sizeof(unsigned short);

    if (ws_size >= weBytes) {
        unsigned short* WEb = (unsigned short*)d_ws;
        const int nTiles = (nEnt + 15) >> 4;
        const int preBlocks = (nTiles + 7) / 8;   // 2 tiles/wave, 4 waves/block
        we_kernel_mfma<<<preBlocks, 256, 0, stream>>>(entity_emb, W, WEb, nEnt);
        const int mainBlocks = (nPairs + 3) / 4;  // 1 wave/pair (R11 structure)
        kgcn_main<<<mainBlocks, 256, 0, stream>>>(pairs, adj_entity, adj_relation,
                                                  WEb, relation_emb, user_emb,
                                                  W, b, out, nPairs);
    } else {
        const int nBlocks = (nPairs + 1) / 2;
        kgcn_fallback<<<nBlocks, 256, 0, stream>>>(pairs, adj_entity, adj_relation,
                                                   entity_emb, relation_emb, user_emb,
                                                   W, b, out, nPairs);
    }
}